// Round 3
// baseline (416.815 us; speedup 1.0000x reference)
//
#include <hip/hip_runtime.h>

// LocalityLoss: all four losses reduce to per-(t,h) and per-(t,w) sums of x and
// x^2 over the other axes (n_other = 512*56 = 28672 for both), followed by
// prefix/suffix cumsums of 56 values per image.
//
// R3: pure streaming kernel — no LDS staging, no __syncthreads. Each wave
// handles 2 channels. Lane decomposition: ho = lane>>4 (row-offset cluster),
// cq = lane&15 (column quad, active cq<14). Iteration r reads rows 4r..4r+3
// as one contiguous 896B wave-load. Row partials accumulate in 14 register
// pairs (no cross-lane traffic in the loop); one 16-lane butterfly per row
// at the end. Col partials in 4 register pairs, xor-16/32 reduce at end.

constexpr int T = 32, C = 512, H = 56, W = 56;
constexpr int HW = H * W;     // 3136
constexpr int CPB = 8;        // channels per block (2 per wave)
constexpr float EPS = 1e-6f;

__global__ __launch_bounds__(256) void sums_kernel(const float* __restrict__ x,
                                                   float* __restrict__ acc) {
    const int bid = blockIdx.x;
    const int t      = bid >> 6;   // C/CPB == 64 channel-groups
    const int cg_blk = bid & 63;
    const int tid  = threadIdx.x;
    const int wave = tid >> 6;
    const int lane = tid & 63;
    const int ho = lane >> 4;      // 0..3: which of 4 consecutive rows
    const int cq = lane & 15;      // 0..13 active: which float4 within the row
    const bool act = (cq < 14);

    float qr[14], sr[14];                      // row partials: row h = ho + 4r
    #pragma unroll
    for (int r = 0; r < 14; ++r) { qr[r] = 0.f; sr[r] = 0.f; }
    float csq[4] = {0.f, 0.f, 0.f, 0.f};       // col partials: w = cq*4+k
    float cln[4] = {0.f, 0.f, 0.f, 0.f};

    const float* base = x + ((size_t)t * C + (size_t)cg_blk * CPB + (size_t)wave * 2) * HW;

    #pragma unroll
    for (int c = 0; c < 2; ++c) {
        const float* chb = base + c * HW;
        #pragma unroll
        for (int r = 0; r < 14; ++r) {
            float4 v = make_float4(0.f, 0.f, 0.f, 0.f);
            if (act) v = *(const float4*)(chb + (4 * r + ho) * W + cq * 4);
            float xx = v.x * v.x, yy = v.y * v.y, zz = v.z * v.z, ww = v.w * v.w;
            csq[0] += xx; csq[1] += yy; csq[2] += zz; csq[3] += ww;
            cln[0] += v.x; cln[1] += v.y; cln[2] += v.z; cln[3] += v.w;
            qr[r] += xx + yy + zz + ww;
            sr[r] += v.x + v.y + v.z + v.w;
        }
    }

    // ---- row reduction: sum each (qr[r], sr[r]) across the 16-lane cluster ----
    float rowq = 0.f, rowl = 0.f;
    #pragma unroll
    for (int r = 0; r < 14; ++r) {
        float q = qr[r], s = sr[r];
        #pragma unroll
        for (int m = 1; m < 16; m <<= 1) {
            q += __shfl_xor(q, m, 16);
            s += __shfl_xor(s, m, 16);
        }
        if (cq == r) { rowq = q; rowl = s; }   // lane keeps row h = ho + 4*cq
    }
    // ---- col reduction: sum across the 4 ho-clusters ----
    #pragma unroll
    for (int k = 0; k < 4; ++k) {
        csq[k] += __shfl_xor(csq[k], 16, 64);
        csq[k] += __shfl_xor(csq[k], 32, 64);
        cln[k] += __shfl_xor(cln[k], 16, 64);
        cln[k] += __shfl_xor(cln[k], 32, 64);
    }

    // acc layout: [0]=sq_h [1]=lin_h [2]=sq_w [3]=lin_w, each [T][56]
    if (act) {
        int h = ho + 4 * cq;
        atomicAdd(&acc[(0 * T + t) * 56 + h], rowq);
        atomicAdd(&acc[(1 * T + t) * 56 + h], rowl);
        if (ho == 0) {
            #pragma unroll
            for (int k = 0; k < 4; ++k) {
                atomicAdd(&acc[(2 * T + t) * 56 + cq * 4 + k], csq[k]);
                atomicAdd(&acc[(3 * T + t) * 56 + cq * 4 + k], cln[k]);
            }
        }
    }
}

__global__ void finalize_kernel(const float* __restrict__ acc, float* __restrict__ out) {
    const int tid = threadIdx.x;  // one wave; lanes 0..31 handle one t each
    float loss = 0.f;
    if (tid < T) {
        const float n_other = 28672.0f;  // 512*56 for both axes
        for (int pair = 0; pair < 2; ++pair) {
            const float* sq  = acc + (pair * 2 + 0) * T * 56 + tid * 56;
            const float* lin = acc + (pair * 2 + 1) * T * 56 + tid * 56;
            float psq = 0.f, plin = 0.f, ssq = 0.f, slin = 0.f;
            for (int i = 0; i < 56; ++i) {
                psq += sq[i];      plin += lin[i];
                ssq += sq[55 - i]; slin += lin[55 - i];
                float n = n_other * (float)(i + 1);
                loss += sqrtf(psq + 2.f * EPS * plin + EPS * EPS * n) + EPS;  // prefix [: i+1]
                loss += sqrtf(ssq + 2.f * EPS * slin + EPS * EPS * n) + EPS;  // suffix [55-i :]
            }
        }
    }
    #pragma unroll
    for (int off = 32; off > 0; off >>= 1) loss += __shfl_down(loss, off);
    if (tid == 0) out[0] = loss * (1.0f / 128.0f);  // /4 losses, /32 mean over t
}

extern "C" void kernel_launch(void* const* d_in, const int* in_sizes, int n_in,
                              void* d_out, int out_size, void* d_ws, size_t ws_size,
                              hipStream_t stream) {
    const float* x = (const float*)d_in[0];
    float* out = (float*)d_out;
    float* acc = (float*)d_ws;  // 4*32*56 floats = 28672 B

    hipMemsetAsync(acc, 0, 4 * T * 56 * sizeof(float), stream);
    sums_kernel<<<T * (C / CPB), 256, 0, stream>>>(x, acc);
    finalize_kernel<<<1, 64, 0, stream>>>(acc, out);
}

// Round 4
// 296.820 us; speedup vs baseline: 1.4043x; 1.4043x over previous
//
#include <hip/hip_runtime.h>

// LocalityLoss: all four losses reduce to per-(t,h) and per-(t,w) sums of x and
// x^2 over the other axes (n_other = 512*56 = 28672), followed by prefix/suffix
// cumsums of 56 values per image.
//
// R4: R3's streaming loads kept EXACTLY; global atomics removed (theory: memory-
// side fp32 atomics to the 28KB acc were the serializer — R3 WRITE_SIZE=17.9MB
// of atomic write-through, ~9 lane-atomics/ns bound fits R2 and R3 timings).
// Each wave writes 224 partials to its own ws slice; per-t reduce kernel sums
// 256 wave-partials per bin, computes the per-t loss, 32 atomics total.

constexpr int T = 32, C = 512, H = 56, W = 56;
constexpr int HW = H * W;     // 3136
constexpr int CPB = 8;        // channels per block (2 per wave)
constexpr int NWAVES = T * (C / CPB) * 4;  // 8192 total waves
constexpr float EPS = 1e-6f;

__global__ __launch_bounds__(256) void sums_kernel(const float* __restrict__ x,
                                                   float* __restrict__ part) {
    const int bid = blockIdx.x;
    const int t      = bid >> 6;   // C/CPB == 64 channel-groups
    const int cg_blk = bid & 63;
    const int tid  = threadIdx.x;
    const int wave = tid >> 6;
    const int lane = tid & 63;
    const int ho = lane >> 4;      // 0..3: which of 4 consecutive rows
    const int cq = lane & 15;      // 0..13 active: which float4 within the row
    const bool act = (cq < 14);

    float qr[14], sr[14];                      // row partials: row h = ho + 4r
    #pragma unroll
    for (int r = 0; r < 14; ++r) { qr[r] = 0.f; sr[r] = 0.f; }
    float csq[4] = {0.f, 0.f, 0.f, 0.f};       // col partials: w = cq*4+k
    float cln[4] = {0.f, 0.f, 0.f, 0.f};

    const float* base = x + ((size_t)t * C + (size_t)cg_blk * CPB + (size_t)wave * 2) * HW;

    #pragma unroll
    for (int c = 0; c < 2; ++c) {
        const float* chb = base + c * HW;
        #pragma unroll
        for (int r = 0; r < 14; ++r) {
            float4 v = make_float4(0.f, 0.f, 0.f, 0.f);
            if (act) v = *(const float4*)(chb + (4 * r + ho) * W + cq * 4);
            float xx = v.x * v.x, yy = v.y * v.y, zz = v.z * v.z, ww = v.w * v.w;
            csq[0] += xx; csq[1] += yy; csq[2] += zz; csq[3] += ww;
            cln[0] += v.x; cln[1] += v.y; cln[2] += v.z; cln[3] += v.w;
            qr[r] += xx + yy + zz + ww;
            sr[r] += v.x + v.y + v.z + v.w;
        }
    }

    // ---- row reduction: sum each (qr[r], sr[r]) across the 16-lane cluster ----
    float rowq = 0.f, rowl = 0.f;
    #pragma unroll
    for (int r = 0; r < 14; ++r) {
        float q = qr[r], s = sr[r];
        #pragma unroll
        for (int m = 1; m < 16; m <<= 1) {
            q += __shfl_xor(q, m, 16);
            s += __shfl_xor(s, m, 16);
        }
        if (cq == r) { rowq = q; rowl = s; }   // lane keeps row h = ho + 4*cq
    }
    // ---- col reduction: sum across the 4 ho-clusters ----
    #pragma unroll
    for (int k = 0; k < 4; ++k) {
        csq[k] += __shfl_xor(csq[k], 16, 64);
        csq[k] += __shfl_xor(csq[k], 32, 64);
        cln[k] += __shfl_xor(cln[k], 16, 64);
        cln[k] += __shfl_xor(cln[k], 32, 64);
    }

    // ---- per-wave partial write (no atomics) ----
    // layout per wave: [0:56)=row_sq [56:112)=row_lin [112:168)=col_sq [168:224)=col_lin
    float* wbase = part + (size_t)(bid * 4 + wave) * 224;
    if (act) {
        int h = ho + 4 * cq;
        wbase[h]      = rowq;
        wbase[56 + h] = rowl;
        if (ho == 0) {
            #pragma unroll
            for (int k = 0; k < 4; ++k) {
                wbase[112 + cq * 4 + k] = csq[k];
                wbase[168 + cq * 4 + k] = cln[k];
            }
        }
    }
}

// One block per image t: sum this t's 256 wave-partials into tot[224], then
// compute the per-t loss and add into out[0].
__global__ __launch_bounds__(256) void reduce_kernel(const float* __restrict__ part,
                                                     float* __restrict__ out) {
    __shared__ float tot[224];
    const int t = blockIdx.x;
    const int tid = threadIdx.x;
    const float* base = part + (size_t)t * 256 * 224;
    if (tid < 224) {
        float s = 0.f;
        #pragma unroll 8
        for (int w = 0; w < 256; ++w) s += base[(size_t)w * 224 + tid];
        tot[tid] = s;
    }
    __syncthreads();
    if (tid < 2) {
        // tid 0: rows (h axis); tid 1: cols (w axis)
        const float n_other = 28672.0f;  // 512*56 for both axes
        const float* sq  = &tot[tid * 112];
        const float* lin = &tot[tid * 112 + 56];
        float loss = 0.f;
        float psq = 0.f, plin = 0.f, ssq = 0.f, slin = 0.f;
        for (int i = 0; i < 56; ++i) {
            psq += sq[i];      plin += lin[i];
            ssq += sq[55 - i]; slin += lin[55 - i];
            float n = n_other * (float)(i + 1);
            loss += sqrtf(psq + 2.f * EPS * plin + EPS * EPS * n) + EPS;  // prefix
            loss += sqrtf(ssq + 2.f * EPS * slin + EPS * EPS * n) + EPS;  // suffix
        }
        atomicAdd(out, loss * (1.0f / 128.0f));  // /4 losses, /32 mean over t
    }
}

extern "C" void kernel_launch(void* const* d_in, const int* in_sizes, int n_in,
                              void* d_out, int out_size, void* d_ws, size_t ws_size,
                              hipStream_t stream) {
    const float* x = (const float*)d_in[0];
    float* out = (float*)d_out;
    float* part = (float*)d_ws;  // 8192 waves x 224 floats = 7.34 MB

    hipMemsetAsync(out, 0, sizeof(float), stream);
    sums_kernel<<<T * (C / CPB), 256, 0, stream>>>(x, part);
    reduce_kernel<<<T, 256, 0, stream>>>(part, out);
}

// Round 5
// 295.218 us; speedup vs baseline: 1.4119x; 1.0054x over previous
//
#include <hip/hip_runtime.h>

// LocalityLoss: all four losses reduce to per-(t,h) and per-(t,w) sums of x and
// x^2 over the other axes (n_other = 512*56 = 28672), then prefix/suffix
// cumsums of 56 values per image.
//
// R5: R2's LDS-staged coalesced load structure (proven load path; its ~100us
// was the 917K lane-atomics @ ~9/ns, not the loads) + R4's no-atomic finish
// (proven: removing atomics cut exactly the predicted 120us). Each wave writes
// its 112 partials to a private ws slice; per-t reduce kernel sums 128
// wave-partials per bin and computes the loss inline. 32 atomics total.

constexpr int T = 32, C = 512, H = 56, W = 56;
constexpr int HW = H * W;     // 3136 floats per channel slice
constexpr int PADW = 60;      // LDS row stride: 16B-aligned rows, breaks pow2 conflicts
constexpr int CPB = 8;        // channels per block
constexpr float EPS = 1e-6f;

__global__ __launch_bounds__(256) void sums_kernel(const float* __restrict__ x,
                                                   float* __restrict__ part) {
    __shared__ float tile[2][H * PADW];  // 2 x 13440 B = 26.9 KB -> 5 blocks/CU
    const int bid = blockIdx.x;
    const int t  = bid >> 6;   // C/CPB == 64 channel-groups
    const int cg = bid & 63;
    const float* base = x + ((size_t)t * C + (size_t)cg * CPB) * HW;

    const int tid  = threadIdx.x;
    const int wave = tid >> 6;
    const int lane = tid & 63;
    const int my_tile = wave >> 1;      // waves 0,1 -> tile0; waves 2,3 -> tile1
    const int role    = wave & 1;       // 0 = rows (h), 1 = cols (w)

    float a0 = 0.f, a1 = 0.f;           // (sumsq, sum)

    for (int it = 0; it < 4; ++it) {
        // channels 2*it and 2*it+1 are contiguous: one 1568-float4 stream
        const float4* src = (const float4*)(base + (size_t)(2 * it) * HW);
        __syncthreads();  // previous tiles fully consumed
        #pragma unroll
        for (int i = 0; i < 7; ++i) {
            int idx = tid + i * 256;
            if (idx < 2 * HW / 4) {     // 1568
                float4 v = src[idx];
                int tl = idx >= 784;
                int j  = idx - 784 * tl;     // float4 index within the slice
                int h  = j / 14;             // W/4 == 14 float4s per row
                int w  = (j - h * 14) * 4;
                *(float4*)&tile[tl][h * PADW + w] = v;
            }
        }
        __syncthreads();
        if (role == 0) {
            if (lane < H) {
                const float* rowp = &tile[my_tile][lane * PADW];
                #pragma unroll
                for (int k = 0; k < W / 4; ++k) {
                    float4 v = *(const float4*)&rowp[k * 4];
                    a0 += v.x * v.x + v.y * v.y + v.z * v.z + v.w * v.w;
                    a1 += v.x + v.y + v.z + v.w;
                }
            }
        } else {
            if (lane < W) {
                #pragma unroll 8
                for (int r = 0; r < H; ++r) {
                    float v = tile[my_tile][r * PADW + lane];
                    a0 += v * v;
                    a1 += v;
                }
            }
        }
    }

    // Per-wave partial write, no atomics.
    // Layout per block: wave w at [bid*448 + w*112): [0:56)=sumsq, [56:112)=sum.
    // Waves 0,2 hold row (h) partials; waves 1,3 hold col (w) partials.
    if (lane < 56) {
        float* wbase = part + (size_t)bid * 448 + (size_t)wave * 112;
        wbase[lane]      = a0;
        wbase[56 + lane] = a1;
    }
}

// One block per image t: sum 64 blocks x 2 waves of partials per bin (coalesced
// across tid), then compute the per-t loss and add into out[0].
__global__ __launch_bounds__(256) void reduce_kernel(const float* __restrict__ part,
                                                     float* __restrict__ out) {
    __shared__ float tot[224];  // [0:112)=rows(sq,lin) [112:224)=cols(sq,lin)
    const int t = blockIdx.x;
    const int tid = threadIdx.x;
    const float* base = part + (size_t)t * 64 * 448;
    if (tid < 224) {
        float s = 0.f;
        #pragma unroll 8
        for (int b = 0; b < 64; ++b) {
            s += base[b * 448 + tid];        // waves 0,1
            s += base[b * 448 + 224 + tid];  // waves 2,3
        }
        tot[tid] = s;
    }
    __syncthreads();
    if (tid < 2) {
        // tid 0: rows (h axis); tid 1: cols (w axis)
        const float n_other = 28672.0f;  // 512*56 for both axes
        const float* sq  = &tot[tid * 112];
        const float* lin = &tot[tid * 112 + 56];
        float loss = 0.f;
        float psq = 0.f, plin = 0.f, ssq = 0.f, slin = 0.f;
        for (int i = 0; i < 56; ++i) {
            psq += sq[i];      plin += lin[i];
            ssq += sq[55 - i]; slin += lin[55 - i];
            float n = n_other * (float)(i + 1);
            loss += sqrtf(psq + 2.f * EPS * plin + EPS * EPS * n) + EPS;  // prefix
            loss += sqrtf(ssq + 2.f * EPS * slin + EPS * EPS * n) + EPS;  // suffix
        }
        atomicAdd(out, loss * (1.0f / 128.0f));  // /4 losses, /32 mean over t
    }
}

extern "C" void kernel_launch(void* const* d_in, const int* in_sizes, int n_in,
                              void* d_out, int out_size, void* d_ws, size_t ws_size,
                              hipStream_t stream) {
    const float* x = (const float*)d_in[0];
    float* out = (float*)d_out;
    float* part = (float*)d_ws;  // 2048 blocks x 448 floats = 3.67 MB

    hipMemsetAsync(out, 0, sizeof(float), stream);
    sums_kernel<<<T * (C / CPB), 256, 0, stream>>>(x, part);
    reduce_kernel<<<T, 256, 0, stream>>>(part, out);
}

// Round 6
// 293.332 us; speedup vs baseline: 1.4210x; 1.0064x over previous
//
#include <hip/hip_runtime.h>

// LocalityLoss: all four losses reduce to per-(t,h) and per-(t,w) sums of x and
// x^2 over the other axes (n_other = 512*56 = 28672), then prefix/suffix
// cumsums of 56 values per image.
//
// R6: software-pipelined LDS staging. CPB=4 -> 4096 blocks (16/CU queued).
// Per round: issue next channel's global loads into VGPRs, reduce current
// channel from LDS (all 4 waves: rows split by k-half, cols by r-half), then
// ds_write the prefetched data and barrier. Loads stay in flight across the
// reduce phase -> no HBM-idle convoy. One barrier per round.

constexpr int T = 32, C = 512, H = 56, W = 56;
constexpr int HW = H * W;       // 3136
constexpr int PADW = 60;        // row stride 240B: 16B-aligned, breaks pow2 conflicts
constexpr int CPB = 4;          // channels per block, 1 per pipeline round
constexpr float EPS = 1e-6f;

__global__ __launch_bounds__(256) void sums_kernel(const float* __restrict__ x,
                                                   float* __restrict__ part) {
    __shared__ float tile[2][H * PADW];   // 2 x 13.44 KB = 26.9 KB -> 5 blocks/CU
    const int bid = blockIdx.x;
    const int t  = bid >> 7;              // C/CPB == 128 channel-groups
    const int cg = bid & 127;
    const float* base = x + ((size_t)t * C + (size_t)cg * CPB) * HW;

    const int tid  = threadIdx.x;
    const int wave = tid >> 6;
    const int lane = tid & 63;
    const int role = wave & 1;            // 0 = rows (h), 1 = cols (w)
    const int half = wave >> 1;           // k-half (rows) / r-half (cols)

    float a0 = 0.f, a1 = 0.f;             // (sumsq, sum)

    // prologue: stage channel 0 into tile[0]
    {
        const float4* src = (const float4*)base;
        #pragma unroll
        for (int i = 0; i < 4; ++i) {
            int idx = tid + i * 256;
            if (idx < 784) {
                float4 v = src[idx];
                int h = idx / 14, w = (idx - h * 14) * 4;
                *(float4*)&tile[0][h * PADW + w] = v;
            }
        }
    }
    __syncthreads();

    #pragma unroll
    for (int c = 1; c <= CPB; ++c) {
        // (1) issue prefetch loads for channel c (stay in flight during reduce)
        float4 nxt[4];
        if (c < CPB) {
            const float4* src = (const float4*)(base + (size_t)c * HW);
            #pragma unroll
            for (int i = 0; i < 4; ++i) {
                int idx = tid + i * 256;
                nxt[i] = (idx < 784) ? src[idx] : make_float4(0.f, 0.f, 0.f, 0.f);
            }
        }
        // (2) reduce channel c-1 from tile[(c-1)&1] (LDS only, independent)
        const float* tl = tile[(c - 1) & 1];
        if (role == 0) {
            if (lane < H) {
                const float* rowp = &tl[lane * PADW + half * 28];
                #pragma unroll
                for (int k = 0; k < 7; ++k) {
                    float4 v = *(const float4*)&rowp[k * 4];
                    a0 += v.x * v.x + v.y * v.y + v.z * v.z + v.w * v.w;
                    a1 += v.x + v.y + v.z + v.w;
                }
            }
        } else {
            if (lane < W) {
                #pragma unroll 7
                for (int r = half * 28; r < half * 28 + 28; ++r) {
                    float v = tl[r * PADW + lane];
                    a0 += v * v;
                    a1 += v;
                }
            }
        }
        // (3) commit prefetched data to the other tile, barrier
        if (c < CPB) {
            #pragma unroll
            for (int i = 0; i < 4; ++i) {
                int idx = tid + i * 256;
                if (idx < 784) {
                    int h = idx / 14, w = (idx - h * 14) * 4;
                    *(float4*)&tile[c & 1][h * PADW + w] = nxt[i];
                }
            }
        }
        __syncthreads();
    }

    // Per-wave partial write, no atomics.
    // Block slice (448 floats): [w0 rows sq|lin][w1 cols sq|lin][w2 rows][w3 cols]
    if (lane < 56) {
        float* wbase = part + (size_t)bid * 448 + (size_t)wave * 112;
        wbase[lane]      = a0;
        wbase[56 + lane] = a1;
    }
}

// One block per image t (512 threads): two thread-groups each sum half the 128
// block-slices for all 224 bins, LDS-combine, then compute the per-t loss.
__global__ __launch_bounds__(512) void reduce_kernel(const float* __restrict__ part,
                                                     float* __restrict__ out) {
    __shared__ float tot2[2][224];
    const int t = blockIdx.x;
    const int tid = threadIdx.x;
    const float* base = part + (size_t)t * 128 * 448;
    if (tid < 448) {
        int g = tid / 224, bin = tid - g * 224;
        float s = 0.f;
        #pragma unroll 8
        for (int b = g * 64; b < g * 64 + 64; ++b) {
            s += base[b * 448 + bin];        // waves 0,1
            s += base[b * 448 + 224 + bin];  // waves 2,3
        }
        tot2[g][bin] = s;
    }
    __syncthreads();
    if (tid < 2) {
        // tid 0: rows (bins 0..111); tid 1: cols (bins 112..223)
        const float n_other = 28672.0f;  // 512*56 for both axes
        const int o = tid * 112;
        float loss = 0.f;
        float psq = 0.f, plin = 0.f, ssq = 0.f, slin = 0.f;
        for (int i = 0; i < 56; ++i) {
            float sqi  = tot2[0][o + i]       + tot2[1][o + i];
            float lini = tot2[0][o + 56 + i]  + tot2[1][o + 56 + i];
            float sqj  = tot2[0][o + 55 - i]      + tot2[1][o + 55 - i];
            float linj = tot2[0][o + 56 + 55 - i] + tot2[1][o + 56 + 55 - i];
            psq += sqi; plin += lini; ssq += sqj; slin += linj;
            float n = n_other * (float)(i + 1);
            loss += sqrtf(psq + 2.f * EPS * plin + EPS * EPS * n) + EPS;  // prefix
            loss += sqrtf(ssq + 2.f * EPS * slin + EPS * EPS * n) + EPS;  // suffix
        }
        atomicAdd(out, loss * (1.0f / 128.0f));  // /4 losses, /32 mean over t
    }
}

extern "C" void kernel_launch(void* const* d_in, const int* in_sizes, int n_in,
                              void* d_out, int out_size, void* d_ws, size_t ws_size,
                              hipStream_t stream) {
    const float* x = (const float*)d_in[0];
    float* out = (float*)d_out;
    float* part = (float*)d_ws;  // 4096 blocks x 448 floats = 7.34 MB

    hipMemsetAsync(out, 0, sizeof(float), stream);
    sums_kernel<<<T * (C / CPB), 256, 0, stream>>>(x, part);
    reduce_kernel<<<T, 512, 0, stream>>>(part, out);
}